// Round 3
// baseline (321.192 us; speedup 1.0000x reference)
//
#include <hip/hip_runtime.h>
#include <hip/hip_bf16.h>
#include <stdint.h>
#include <math.h>

// ---------------------------------------------------------------------------
// MHA: x[8192,1024] (fp32 or bf16, detected) -> bf16 -> qkv GEMM
// -> causal flash attn -> proj + bias.
// Round-10: GEMM latency-bound fix (r2: MfmaUtil pinned 22%, occ 17%, HBM 18%
// -> loads not covered, no TLP).  New gemm: 256x128 tile, 8 waves (512thr),
// BK=64, ring-3 LDS (144KB), counted s_waitcnt vmcnt(6) + raw s_barrier
// (ONE per K-step, never drains the pipe), prefetch issued 2 K-steps ahead
// (~2 iters > HBM latency).  Proven 128B-row XOR swizzle kept (conflicts=0).
// Race safety: STAGE(t+2) writes ring slot whose readers (iter t-1) finished
// ds_reads before crossing iter-t barrier; in-loop VMEM = only the 6 gl16s
// (g_isf32/bias reads fenced outside the loop).
// ---------------------------------------------------------------------------

typedef __attribute__((ext_vector_type(8))) short short8;   // 8 x bf16 frag
typedef __attribute__((ext_vector_type(4))) float f32x4;    // C/D frag

#define LOG2E 1.44269504088896340736f
#define QSCALE 0.18033688011112042f    /* 0.125 * LOG2E, folded into Q */

__device__ int g_isf32;   // 1 if inputs/outputs are fp32, 0 if bf16

__device__ __forceinline__ void gl16(const void* g, void* l) {
  __builtin_amdgcn_global_load_lds(
      (const __attribute__((address_space(1))) unsigned int*)g,
      (__attribute__((address_space(3))) unsigned int*)l, 16, 0, 0);
}

__device__ __forceinline__ short f2bf(float f) {
  __hip_bfloat16 h = __float2bfloat16(f);
  return *reinterpret_cast<short*>(&h);
}
__device__ __forceinline__ float bf2f(short s) {
  __hip_bfloat16 h = *reinterpret_cast<__hip_bfloat16*>(&s);
  return __bfloat162float(h);
}
__device__ __forceinline__ short8 pack8(f32x4 lo, f32x4 hi) {
  short8 r;
#pragma unroll
  for (int e = 0; e < 4; ++e) { r[e] = f2bf(lo[e]); r[4 + e] = f2bf(hi[e]); }
  return r;
}

// cheap bf16 round (ties-up) for known-positive, non-NaN values (P weights)
__device__ __forceinline__ short pbf(float f) {
  unsigned u = __builtin_bit_cast(unsigned, f);
  return (short)((u + 0x8000u) >> 16);
}

// 16-lane butterfly reductions via DPP (pure VALU; no ds_swizzle).
__device__ __forceinline__ float dpp_max16(float x) {
  int i;
  i = __builtin_amdgcn_update_dpp(0, __builtin_bit_cast(int, x), 0xB1, 0xF, 0xF, true);
  x = fmaxf(x, __builtin_bit_cast(float, i));
  i = __builtin_amdgcn_update_dpp(0, __builtin_bit_cast(int, x), 0x4E, 0xF, 0xF, true);
  x = fmaxf(x, __builtin_bit_cast(float, i));
  i = __builtin_amdgcn_update_dpp(0, __builtin_bit_cast(int, x), 0x141, 0xF, 0xF, true);
  x = fmaxf(x, __builtin_bit_cast(float, i));
  i = __builtin_amdgcn_update_dpp(0, __builtin_bit_cast(int, x), 0x140, 0xF, 0xF, true);
  x = fmaxf(x, __builtin_bit_cast(float, i));
  return x;
}
__device__ __forceinline__ float dpp_sum16(float x) {
  int i;
  i = __builtin_amdgcn_update_dpp(0, __builtin_bit_cast(int, x), 0xB1, 0xF, 0xF, true);
  x += __builtin_bit_cast(float, i);
  i = __builtin_amdgcn_update_dpp(0, __builtin_bit_cast(int, x), 0x4E, 0xF, 0xF, true);
  x += __builtin_bit_cast(float, i);
  i = __builtin_amdgcn_update_dpp(0, __builtin_bit_cast(int, x), 0x141, 0xF, 0xF, true);
  x += __builtin_bit_cast(float, i);
  i = __builtin_amdgcn_update_dpp(0, __builtin_bit_cast(int, x), 0x140, 0xF, 0xF, true);
  x += __builtin_bit_cast(float, i);
  return x;
}

// ---------------------------------------------------------------------------
// Dtype detection from w_qkv bit patterns.
// ---------------------------------------------------------------------------
__global__ __launch_bounds__(256) void detect_dtype(const unsigned short* w) {
  __shared__ int cnt;
  if (threadIdx.x == 0) cnt = 0;
  __syncthreads();
  const unsigned short* p = w + (long)blockIdx.x * 49152;
  int c = 0;
  for (int i = threadIdx.x; i < 49152; i += 256)
    if (((p[i] >> 7) & 0xFF) == 0xFF) c++;
  atomicAdd(&cnt, c);
  __syncthreads();
  if (threadIdx.x == 0) g_isf32 = (cnt > 8) ? 1 : 0;
}

// ---------------------------------------------------------------------------
// x -> bf16 copy/convert (8 elems per thread)
// ---------------------------------------------------------------------------
__global__ __launch_bounds__(256) void cvt_x(const void* __restrict__ src,
                                             short* __restrict__ dst) {
  const long i = ((long)blockIdx.x * 256 + threadIdx.x) * 8;
  if (g_isf32) {
    const float* s = (const float*)src + i;
    *(short8*)(dst + i) = pack8(*(const f32x4*)s, *(const f32x4*)(s + 4));
  } else {
    *(short8*)(dst + i) = *(const short8*)((const short*)src + i);
  }
}

// ---------------------------------------------------------------------------
// gemm_bt: C = A[M,K]*Bt[N,K]^T.  BM=256 BN=128 BK=64, 8 waves (4M x 2N,
// wave tile 64x64), ring-3 LDS, counted-vmcnt pipeline (see header).
// LDS row layout (128B rows): slot(row, cs) holds global chunk cs^(row&7).
// MODE 1: C(+bias), dtype per g_isf32. MODE 2: qkv split epilogue (bf16):
//   col<1024 -> Q pre-scaled -> qk; col<2048 -> K -> qk; else V^T -> vt.
// ---------------------------------------------------------------------------
template <int MODE>
__global__ __launch_bounds__(512, 2) void gemm_bt(
    const short* __restrict__ A, const short* __restrict__ Bt,
    const void* __restrict__ bias, void* __restrict__ C,
    short* __restrict__ vt, int M, int N, int K)
{
  __shared__ __align__(16) short As[3][16384];   // 3 x 32KB
  __shared__ __align__(16) short Bs[3][8192];    // 3 x 16KB
  const int tid  = threadIdx.x;
  const int lane = tid & 63;
  const int wave = tid >> 6;
  const int quad = lane >> 4;
  const int l16  = lane & 15;
  const int wm = (wave >> 1) * 64;   // 0..192 within 256-row tile
  const int wn = (wave & 1) * 64;    // 0..64  within 128-col tile

  // XCD-aware bijective block swizzle (grids here are multiples of 8)
  const int gx = (int)gridDim.x;
  const int nwg = gx * (int)gridDim.y;
  int lb = (int)blockIdx.y * gx + (int)blockIdx.x;
  if ((nwg & 7) == 0) lb = (lb & 7) * (nwg >> 3) + (lb >> 3);
  const long m0 = (long)(lb / gx) * 256;
  const long n0 = (long)(lb % gx) * 128;

  // MODE 1 reads g_isf32; fence it so in-loop vmcnt counting stays exact.
  int isf32 = 0;
  if (MODE == 1) {
    isf32 = g_isf32;
    asm volatile("s_waitcnt vmcnt(0) lgkmcnt(0)" ::: "memory");
  }

  f32x4 acc[4][4] = {};

  // staging: slot idx = g*512+tid; row = g*64 + (tid>>3); stored chunk tid&7
  // holds global chunk (tid&7)^(row&7)  (row&7 == (tid>>3)&7 for all g)
  const int srow = tid >> 3;
  const int scol = ((tid & 7) ^ (srow & 7)) * 8;   // shorts
  const short* Ag = A  + (m0 + srow) * (long)K + scol;
  const short* Bg = Bt + (n0 + srow) * (long)K + scol;
  const long rs64 = (long)64 * K;

  // ds-read bases: frag row&7 == l16&7; byte = row*128 + (chunk^(l16&7))*16
  const int x7  = l16 & 7;
  const int xo0 = ((0 + quad) ^ x7) * 16;   // K 0-31
  const int xo1 = ((4 + quad) ^ x7) * 16;   // K 32-63
  const int aRow = (wm + l16) * 128;
  const int bRow = (wn + l16) * 128;

  auto STAGE = [&](int t) {
    const int b = t % 3;
    const long k0 = (long)t << 6;
#pragma unroll
    for (int g = 0; g < 4; ++g)
      gl16(Ag + k0 + g * rs64, (char*)As[b] + g * 8192 + tid * 16);
#pragma unroll
    for (int g = 0; g < 2; ++g)
      gl16(Bg + k0 + g * rs64, (char*)Bs[b] + g * 8192 + tid * 16);
  };

  const int nt = K >> 6;     // 16 for K=1024
  STAGE(0);
  STAGE(1);

  for (int t = 0; t < nt; ++t) {
    // retire STAGE(t); keep STAGE(t+1)'s 6 loads in flight (never drain)
    if (t + 1 < nt) { asm volatile("s_waitcnt vmcnt(6)" ::: "memory"); }
    else            { asm volatile("s_waitcnt vmcnt(0)" ::: "memory"); }
    __builtin_amdgcn_sched_barrier(0);
    __builtin_amdgcn_s_barrier();     // buf[t%3] ready for all; iter t-1 reads done
    if (t + 2 < nt) STAGE(t + 2);     // free ring slot (readers were iter t-1)

    const char* Ab = (const char*)As[t % 3];
    const char* Bb = (const char*)Bs[t % 3];
    short8 af[4][2], bfv[4][2];
#pragma unroll
    for (int i = 0; i < 4; ++i) {
      af[i][0] = *(const short8*)(Ab + aRow + i * 2048 + xo0);
      af[i][1] = *(const short8*)(Ab + aRow + i * 2048 + xo1);
    }
#pragma unroll
    for (int j = 0; j < 4; ++j) {
      bfv[j][0] = *(const short8*)(Bb + bRow + j * 2048 + xo0);
      bfv[j][1] = *(const short8*)(Bb + bRow + j * 2048 + xo1);
    }
    __builtin_amdgcn_s_setprio(1);
#pragma unroll
    for (int i = 0; i < 4; ++i)
#pragma unroll
      for (int j = 0; j < 4; ++j) {
        acc[i][j] = __builtin_amdgcn_mfma_f32_16x16x32_bf16(af[i][0], bfv[j][0], acc[i][j], 0, 0, 0);
        acc[i][j] = __builtin_amdgcn_mfma_f32_16x16x32_bf16(af[i][1], bfv[j][1], acc[i][j], 0, 0, 0);
      }
    __builtin_amdgcn_s_setprio(0);
  }

#pragma unroll
  for (int j = 0; j < 4; ++j) {
    const long col = n0 + wn + j * 16 + l16;
    float bv = 0.f;
    if (MODE == 1)
      bv = isf32 ? ((const float*)bias)[col] : bf2f(((const short*)bias)[col]);
#pragma unroll
    for (int i = 0; i < 4; ++i) {
      const long row0 = m0 + wm + i * 16 + quad * 4;
#pragma unroll
      for (int r = 0; r < 4; ++r) {
        const long row = row0 + r;
        const float val = acc[i][j][r] + bv;
        if (MODE == 2) {
          if (col < 2048) {
            const float vq = (col < 1024) ? val * QSCALE : val;
            ((short*)C)[row * 2048 + col] = f2bf(vq);
          } else {
            const long b = row >> 11, t = row & 2047;
            const long hd = col - 2048;            // h*64 + d
            vt[((b * 16 + (hd >> 6)) * 64 + (hd & 63)) * 2048 + t] = f2bf(val);
          }
        } else {
          if (isf32) ((float*)C)[row * (long)N + col] = val;
          else       ((short*)C)[row * (long)N + col] = f2bf(val);
        }
      }
    }
  }
}

// ---------------------------------------------------------------------------
// 64x64 transpose + cast-to-bf16: dst[C,R] = (bf16)src[R,C]^T
// ---------------------------------------------------------------------------
__global__ __launch_bounds__(256) void transpose64(
    const void* __restrict__ src, short* __restrict__ dst, int R, int C)
{
  __shared__ __align__(16) short tile[64][72];
  const int isf32 = g_isf32;
  const int tid = threadIdx.x;
  const long r0 = (long)blockIdx.y * 64;
  const long c0 = (long)blockIdx.x * 64;
#pragma unroll
  for (int it = 0; it < 2; ++it) {
    int idx = it * 256 + tid;
    int rr = idx >> 3, ch = idx & 7;
    const long off = (r0 + rr) * C + c0 + ch * 8;
    short8 v;
    if (isf32) {
      const float* s = (const float*)src + off;
      v = pack8(*(const f32x4*)s, *(const f32x4*)(s + 4));
    } else {
      v = *(const short8*)((const short*)src + off);
    }
    *(short8*)&tile[rr][ch * 8] = v;
  }
  __syncthreads();
#pragma unroll
  for (int it = 0; it < 2; ++it) {
    int idx = it * 256 + tid;
    int cc = idx >> 3, ch = idx & 7;
    short8 v;
#pragma unroll
    for (int jj = 0; jj < 8; ++jj) v[jj] = tile[ch * 8 + jj][cc];
    *(short8*)&dst[(c0 + cc) * R + r0 + ch * 8] = v;
  }
}

// ---------------------------------------------------------------------------
// Flash attention (causal) — unchanged from round 8/9.
// ---------------------------------------------------------------------------
__global__ __launch_bounds__(256) void attn_fwd(
    const short* __restrict__ qk, const short* __restrict__ vt,
    short* __restrict__ out)
{
  __shared__ __align__(16) short Ks[2][64][32];   // [d-half][k-row][d%32]
  __shared__ __align__(16) short Vs[2][64][32];   // [k-half][d][k%32]
  __shared__ __align__(16) short Pw[4][16][76];   // wave-private P, bf16
  const int tid = threadIdx.x;
  const int lane = tid & 63, wave = tid >> 6;
  const int quad = lane >> 4, l16 = lane & 15;
  const int bh = blockIdx.x;
  const int b = bh >> 4, h = bh & 15;
  const int jq = (int)gridDim.y - 1 - (int)blockIdx.y;  // big-work blocks first
  const int qbase = jq * 64 + wave * 16;

  // Q A-frags (rows qbase+l16, two 32-wide d slices); Q is pre-scaled
  const short* qp = qk + ((long)(b * 2048 + qbase + l16)) * 2048 + h * 64 + quad * 8;
  const short8 aq0 = *(const short8*)qp;
  const short8 aq1 = *(const short8*)(qp + 32);

  // staging sources: row sr (k-row for K, d for V), 16B chunk sc_
  const int sr = tid >> 2, sc_ = tid & 3;
  const short* kg = qk + (long)b * 2048 * 2048 + 1024 + h * 64 + (long)sr * 2048 + sc_ * 8;
  const short* vg = vt + ((long)bh * 64 + sr) * 2048 + sc_ * 8;

  f32x4 o[4] = {};
  float m_run[4], l_run[4];
#pragma unroll
  for (int r = 0; r < 4; ++r) { m_run[r] = -1e30f; l_run[r] = 0.f; }

  // ------------------- main tiles: k0+63 < qbase, no masking ----------------
  for (int kt = 0; kt < jq; ++kt) {
    const int k0 = kt * 64;

    __syncthreads();                            // prev-tile readers done
    gl16(kg + (long)k0 * 2048,      (char*)Ks + tid * 16);         // d 0-31
    gl16(kg + (long)k0 * 2048 + 32, (char*)Ks + 4096 + tid * 16);  // d 32-63
    gl16(vg + k0,                   (char*)Vs + tid * 16);         // k 0-31
    gl16(vg + k0 + 32,              (char*)Vs + 4096 + tid * 16);  // k 32-63
    __syncthreads();                            // staging visible

    // S = Q K^T : 4 col-tiles, kdim 64 = 2 MFMA each (already log2-scaled)
    f32x4 s[4];
#pragma unroll
    for (int c = 0; c < 4; ++c) {
      short8 kf0 = *(const short8*)&Ks[0][c * 16 + l16][quad * 8];
      short8 kf1 = *(const short8*)&Ks[1][c * 16 + l16][quad * 8];
      f32x4 z = {};
      z = __builtin_amdgcn_mfma_f32_16x16x32_bf16(aq0, kf0, z, 0, 0, 0);
      z = __builtin_amdgcn_mfma_f32_16x16x32_bf16(aq1, kf1, z, 0, 0, 0);
      s[c] = z;
    }

    // row max: tile-combine then DPP butterfly (pure VALU)
    float mx[4];
#pragma unroll
    for (int r = 0; r < 4; ++r)
      mx[r] = dpp_max16(fmaxf(fmaxf(s[0][r], s[1][r]), fmaxf(s[2][r], s[3][r])));

    // T13 defer-max: rescale only when some row grew by > 8 (log2 domain)
    int grow = 0;
#pragma unroll
    for (int r = 0; r < 4; ++r) grow |= (mx[r] > m_run[r] + 8.f);
    if (__any(grow)) {
#pragma unroll
      for (int r = 0; r < 4; ++r) {
        const float mn = fmaxf(m_run[r], mx[r]);
        const float al = __builtin_amdgcn_exp2f(m_run[r] - mn);
        m_run[r] = mn;
        l_run[r] *= al;
#pragma unroll
        for (int i = 0; i < 4; ++i) o[i][r] *= al;
      }
    }

    // P = exp2(S - m), accumulate l, store bf16 to wave-private LDS
#pragma unroll
    for (int c = 0; c < 4; ++c)
#pragma unroll
      for (int r = 0; r < 4; ++r) {
        const float p = __builtin_amdgcn_exp2f(s[c][r] - m_run[r]);
        l_run[r] += p;
        Pw[wave][quad * 4 + r][c * 16 + l16] = pbf(p);
      }

    // O += P V
    {
      short8 pf0 = *(const short8*)&Pw[wave][l16][quad * 8];
      short8 pf1 = *(const short8*)&Pw[wave][l16][32 + quad * 8];
#pragma unroll
      for (int i = 0; i < 4; ++i) {
        short8 vf0 = *(const short8*)&Vs[0][i * 16 + l16][quad * 8];
        o[i] = __builtin_amdgcn_mfma_f32_16x16x32_bf16(pf0, vf0, o[i], 0, 0, 0);
        short8 vf1 = *(const short8*)&Vs[1][i * 16 + l16][quad * 8];
        o[i] = __builtin_amdgcn_mfma_f32_16x16x32_bf16(pf1, vf1, o[i], 0, 0, 0);
      }
    }
  }

  // ------------------- diagonal tile: kt = jq ------------------------------
  {
    const int k0 = jq * 64;

    __syncthreads();
    gl16(kg + (long)k0 * 2048,      (char*)Ks + tid * 16);
    gl16(kg + (long)k0 * 2048 + 32, (char*)Ks + 4096 + tid * 16);
    gl16(vg + k0,                   (char*)Vs + tid * 16);
    gl16(vg + k0 + 32,              (char*)Vs + 4096 + tid * 16);
    __syncthreads();

    // live c-tiles: c <= wave.  Only c == wave straddles the diagonal.
    f32x4 s[4];
    float mx[4];
#pragma unroll
    for (int r = 0; r < 4; ++r) mx[r] = -1e30f;
#pragma unroll
    for (int c = 0; c < 4; ++c) {
      if (c > wave) continue;                   // wave-uniform
      short8 kf0 = *(const short8*)&Ks[0][c * 16 + l16][quad * 8];
      short8 kf1 = *(const short8*)&Ks[1][c * 16 + l16][quad * 8];
      f32x4 z = {};
      z = __builtin_amdgcn_mfma_f32_16x16x32_bf16(aq0, kf0, z, 0, 0, 0);
      z = __builtin_amdgcn_mfma_f32_16x16x32_bf16(aq1, kf1, z, 0, 0, 0);
      if (c == wave) {
#pragma unroll
        for (int r = 0; r < 4; ++r)
          z[r] = (l16 > quad * 4 + r) ? -1e30f : z[r];
      }
      s[c] = z;
#pragma unroll
      for (int r = 0; r < 4; ++r) mx[r] = fmaxf(mx[r], z[r]);
    }
#pragma unroll
    for (int r = 0; r < 4; ++r) mx[r] = dpp_max16(mx[r]);

    int grow = 0;
#pragma unroll
    for (int r = 0; r < 4; ++r) grow |= (mx[r] > m_run[r] + 8.f);
    if (__any(grow)) {
#pragma unroll
      for (int r = 0; r < 4; ++r) {
        const float mn = fmaxf(m_run[r], mx[r]);
        const float al = __builtin_amdgcn_exp2f(m_run[r] - mn);
        m_run[r] = mn;
        l_run[r] *= al;
#pragma unroll
        for (int i = 0; i < 4; ++i) o[i][r] *= al;
      }
    }

#pragma unroll
    for (int c = 0; c < 4; ++c) {
      if (c <= wave) {
#pragma unroll
        for (int r = 0; r < 4; ++r) {
          const float p = __builtin_amdgcn_exp2f(s[c][r] - m_run[r]);
          l_run[r] += p;
          Pw[wave][quad * 4 + r][c * 16 + l16] = pbf(p);
        }
      } else if (c < 2 || wave >= 2) {
        // dead c inside a live V-half: zero-fill so PV reads zeros
#pragma unroll
        for (int r = 0; r < 4; ++r)
          Pw[wave][quad * 4 + r][c * 16 + l16] = 0;
      }
    }

    {
      short8 pf0 = *(const short8*)&Pw[wave][l16][quad * 8];
#pragma unroll
      for (int i = 0; i < 4; ++i) {
        short8 vf0 = *(const short8*)&Vs[0][i * 16 + l16][quad * 8];
        o[i] = __builtin_amdgcn_mfma_f32_16x16x32_bf16(pf0, vf0, o[i], 0, 0, 0);
      }
      if (wave >= 2) {
        short8 pf1 = *(const short8*)&Pw[wave][l16][32 + quad * 8];
#pragma unroll
        for (int i = 0; i < 4; ++i) {
          short8 vf1 = *(const short8*)&Vs[1][i * 16 + l16][quad * 8];
          o[i] = __builtin_amdgcn_mfma_f32_16x16x32_bf16(pf1, vf1, o[i], 0, 0, 0);
        }
      }
    }
  }

  // final row-sum of per-lane l (DPP butterfly), then normalize + store
#pragma unroll
  for (int r = 0; r < 4; ++r) l_run[r] = dpp_sum16(l_run[r]);
  float inv[4];
#pragma unroll
  for (int r = 0; r < 4; ++r) inv[r] = 1.0f / l_run[r];
  short* op = out + ((long)(b * 2048 + qbase + quad * 4)) * 1024 + h * 64;
#pragma unroll
  for (int i = 0; i < 4; ++i)
#pragma unroll
    for (int r = 0; r < 4; ++r)
      op[(long)r * 1024 + i * 16 + l16] = f2bf(o[i][r] * inv[r]);
}

// ---------------------------------------------------------------------------
// plan-B epilogue copy: projout (qk region) -> d_out
// ---------------------------------------------------------------------------
__global__ __launch_bounds__(256) void copy_out(const void* __restrict__ src,
                                                void* __restrict__ dst)
{
  const long n16 = g_isf32 ? 2097152L : 1048576L;   // uint4 chunks
  const uint4* s = (const uint4*)src;
  uint4* d = (uint4*)dst;
  for (long i = (long)blockIdx.x * 256 + threadIdx.x; i < n16;
       i += (long)gridDim.x * 256)
    d[i] = s[i];
}

// ---------------------------------------------------------------------------
extern "C" void kernel_launch(void* const* d_in, const int* in_sizes, int n_in,
                              void* d_out, int out_size, void* d_ws, size_t ws_size,
                              hipStream_t stream)
{
  const void* x      = d_in[0];   // [8192,1024]  fp32 or bf16
  const void* w_qkv  = d_in[1];   // [1024,3072]
  const void* w_proj = d_in[2];   // [1024,1024]
  const void* b_proj = d_in[3];   // [1024]

  short* ws = (short*)d_ws;
  const bool planA = ws_size >= 67108864ULL;   // 64 MiB

  short* qk  = ws;                 // [8192,2048] bf16    = 32 MiB
  short* vtp = ws + 16777216L;     // [64][64][2048] bf16 = 16 MiB

  short *wqkvT, *attnb, *wprojT, *xbf;
  void*  projC;
  if (planA) {
    attnb  = ws + 25165824L;       // 16 MiB, [48,64) MiB of ws
    wqkvT  = attnb;                // aliased; dead once qkv GEMM reads done
    wprojT = qk;                   // aliased; written after attn_fwd
    xbf    = (short*)d_out;        // 16 MiB in dead d_out; dead after qkv GEMM
    projC  = d_out;
  } else {
    wqkvT  = (short*)d_out;        // d_out dead until the end
    xbf    = (short*)d_out + 3145728L;
    attnb  = (short*)d_out;        // overwrites wqkvT/xbf after both dead
    wprojT = vtp;                  // vtp dead after attn_fwd
    projC  = qk;                   // qk dead after attn_fwd (32 MiB fits fp32)
  }

  // 0. detect dtype; convert x to bf16
  detect_dtype<<<64, 256, 0, stream>>>((const unsigned short*)w_qkv);
  cvt_x<<<4096, 256, 0, stream>>>(x, xbf);
  // 1. W_qkv^T (cast to bf16)
  transpose64<<<dim3(3072 / 64, 1024 / 64), 256, 0, stream>>>(w_qkv, wqkvT, 1024, 3072);
  // 2. qkv GEMM, split epilogue (Q pre-scaled; Q,K row-major bf16; V -> vtp)
  gemm_bt<2><<<dim3(3072 / 128, 8192 / 256), 512, 0, stream>>>(
      xbf, wqkvT, nullptr, qk, vtp, 8192, 3072, 1024);
  // 3. flash attention (LDS-staged K/V)
  attn_fwd<<<dim3(64, 32), 256, 0, stream>>>(qk, vtp, attnb);
  // 4. W_proj^T (cast to bf16)
  transpose64<<<dim3(1024 / 64, 1024 / 64), 256, 0, stream>>>(w_proj, wprojT, 1024, 1024);
  // 5. output projection + bias
  gemm_bt<1><<<dim3(1024 / 128, 8192 / 256), 512, 0, stream>>>(
      attnb, wprojT, b_proj, projC, nullptr, 8192, 1024, 1024);
  // 6. plan-B: move result into d_out
  if (!planA)
    copy_out<<<2048, 256, 0, stream>>>(projC, d_out);
}

// Round 4
// 286.372 us; speedup vs baseline: 1.1216x; 1.1216x over previous
//
#include <hip/hip_runtime.h>
#include <hip/hip_bf16.h>
#include <stdint.h>
#include <math.h>

// ---------------------------------------------------------------------------
// MHA: x[8192,1024] (fp32 or bf16, detected) -> bf16 -> qkv GEMM
// -> causal flash attn -> proj + bias.
// Round-11: fine-phase GEMM (r3's coarse counted-vmcnt was null; m196/m218:
// the per-phase interleave IS the lever).  K-tile body = 2 barrier-delimited
// phases (k-lo/k-hi): {8 ds_read + 3 gl16 half-stage of t+2 -> setprio ->
// 16 MFMA -> setprio -> barrier}; tile top = vmcnt(6) -> barrier (never 0
// in-loop).  Ring-3 LDS (144KB), 256x128 tile, 8 waves, XOR swizzle
// (conflicts=0), XCD block swizzle.  MODE-2 V-epilogue stores merged to
// short4 (4 contiguous t per thread).
// ---------------------------------------------------------------------------

typedef __attribute__((ext_vector_type(8))) short short8;   // 8 x bf16 frag
typedef __attribute__((ext_vector_type(4))) short shrt4;    // 4 x bf16
typedef __attribute__((ext_vector_type(4))) float f32x4;    // C/D frag

#define LOG2E 1.44269504088896340736f
#define QSCALE 0.18033688011112042f    /* 0.125 * LOG2E, folded into Q */

__device__ int g_isf32;   // 1 if inputs/outputs are fp32, 0 if bf16

__device__ __forceinline__ void gl16(const void* g, void* l) {
  __builtin_amdgcn_global_load_lds(
      (const __attribute__((address_space(1))) unsigned int*)g,
      (__attribute__((address_space(3))) unsigned int*)l, 16, 0, 0);
}

__device__ __forceinline__ short f2bf(float f) {
  __hip_bfloat16 h = __float2bfloat16(f);
  return *reinterpret_cast<short*>(&h);
}
__device__ __forceinline__ float bf2f(short s) {
  __hip_bfloat16 h = *reinterpret_cast<__hip_bfloat16*>(&s);
  return __bfloat162float(h);
}
__device__ __forceinline__ short8 pack8(f32x4 lo, f32x4 hi) {
  short8 r;
#pragma unroll
  for (int e = 0; e < 4; ++e) { r[e] = f2bf(lo[e]); r[4 + e] = f2bf(hi[e]); }
  return r;
}

// cheap bf16 round (ties-up) for known-positive, non-NaN values (P weights)
__device__ __forceinline__ short pbf(float f) {
  unsigned u = __builtin_bit_cast(unsigned, f);
  return (short)((u + 0x8000u) >> 16);
}

// 16-lane butterfly reductions via DPP (pure VALU; no ds_swizzle).
__device__ __forceinline__ float dpp_max16(float x) {
  int i;
  i = __builtin_amdgcn_update_dpp(0, __builtin_bit_cast(int, x), 0xB1, 0xF, 0xF, true);
  x = fmaxf(x, __builtin_bit_cast(float, i));
  i = __builtin_amdgcn_update_dpp(0, __builtin_bit_cast(int, x), 0x4E, 0xF, 0xF, true);
  x = fmaxf(x, __builtin_bit_cast(float, i));
  i = __builtin_amdgcn_update_dpp(0, __builtin_bit_cast(int, x), 0x141, 0xF, 0xF, true);
  x = fmaxf(x, __builtin_bit_cast(float, i));
  i = __builtin_amdgcn_update_dpp(0, __builtin_bit_cast(int, x), 0x140, 0xF, 0xF, true);
  x = fmaxf(x, __builtin_bit_cast(float, i));
  return x;
}
__device__ __forceinline__ float dpp_sum16(float x) {
  int i;
  i = __builtin_amdgcn_update_dpp(0, __builtin_bit_cast(int, x), 0xB1, 0xF, 0xF, true);
  x += __builtin_bit_cast(float, i);
  i = __builtin_amdgcn_update_dpp(0, __builtin_bit_cast(int, x), 0x4E, 0xF, 0xF, true);
  x += __builtin_bit_cast(float, i);
  i = __builtin_amdgcn_update_dpp(0, __builtin_bit_cast(int, x), 0x141, 0xF, 0xF, true);
  x += __builtin_bit_cast(float, i);
  i = __builtin_amdgcn_update_dpp(0, __builtin_bit_cast(int, x), 0x140, 0xF, 0xF, true);
  x += __builtin_bit_cast(float, i);
  return x;
}

// ---------------------------------------------------------------------------
// Dtype detection from w_qkv bit patterns.
// ---------------------------------------------------------------------------
__global__ __launch_bounds__(256) void detect_dtype(const unsigned short* w) {
  __shared__ int cnt;
  if (threadIdx.x == 0) cnt = 0;
  __syncthreads();
  const unsigned short* p = w + (long)blockIdx.x * 49152;
  int c = 0;
  for (int i = threadIdx.x; i < 49152; i += 256)
    if (((p[i] >> 7) & 0xFF) == 0xFF) c++;
  atomicAdd(&cnt, c);
  __syncthreads();
  if (threadIdx.x == 0) g_isf32 = (cnt > 8) ? 1 : 0;
}

// ---------------------------------------------------------------------------
// x -> bf16 copy/convert (8 elems per thread)
// ---------------------------------------------------------------------------
__global__ __launch_bounds__(256) void cvt_x(const void* __restrict__ src,
                                             short* __restrict__ dst) {
  const long i = ((long)blockIdx.x * 256 + threadIdx.x) * 8;
  if (g_isf32) {
    const float* s = (const float*)src + i;
    *(short8*)(dst + i) = pack8(*(const f32x4*)s, *(const f32x4*)(s + 4));
  } else {
    *(short8*)(dst + i) = *(const short8*)((const short*)src + i);
  }
}

// ---------------------------------------------------------------------------
// gemm_bt: C = A[M,K]*Bt[N,K]^T.  BM=256 BN=128 BK=64, 8 waves (4M x 2N,
// wave tile 64x64), ring-3 LDS, fine-phase counted-vmcnt pipeline.
// LDS row layout (128B rows): slot(row, cs) holds global chunk cs^(row&7).
// MODE 1: C(+bias), dtype per g_isf32. MODE 2: qkv split epilogue (bf16):
//   col<1024 -> Q pre-scaled -> qk; col<2048 -> K -> qk; else V^T -> vt
//   (vt stores vectorized short4 along t).
// ---------------------------------------------------------------------------
template <int MODE>
__global__ __launch_bounds__(512, 2) void gemm_bt(
    const short* __restrict__ A, const short* __restrict__ Bt,
    const void* __restrict__ bias, void* __restrict__ C,
    short* __restrict__ vt, int M, int N, int K)
{
  __shared__ __align__(16) short As[3][16384];   // 3 x 32KB
  __shared__ __align__(16) short Bs[3][8192];    // 3 x 16KB
  const int tid  = threadIdx.x;
  const int lane = tid & 63;
  const int wave = tid >> 6;
  const int quad = lane >> 4;
  const int l16  = lane & 15;
  const int wm = (wave >> 1) * 64;   // 0..192 within 256-row tile
  const int wn = (wave & 1) * 64;    // 0..64  within 128-col tile

  // XCD-aware bijective block swizzle (grids here are multiples of 8)
  const int gx = (int)gridDim.x;
  const int nwg = gx * (int)gridDim.y;
  int lb = (int)blockIdx.y * gx + (int)blockIdx.x;
  if ((nwg & 7) == 0) lb = (lb & 7) * (nwg >> 3) + (lb >> 3);
  const long m0 = (long)(lb / gx) * 256;
  const long n0 = (long)(lb % gx) * 128;

  // MODE 1 reads g_isf32; fence it so in-loop vmcnt counting stays exact.
  int isf32 = 0;
  if (MODE == 1) {
    isf32 = g_isf32;
    asm volatile("s_waitcnt vmcnt(0) lgkmcnt(0)" ::: "memory");
  }

  f32x4 acc[4][4] = {};

  // staging: row = g*64 + (tid>>3); stored chunk tid&7 holds global chunk
  // (tid&7)^(row&7)   (row&7 == (tid>>3)&7 for all g)
  const int srow = tid >> 3;
  const int scol = ((tid & 7) ^ (srow & 7)) * 8;   // shorts
  const short* Ag = A  + (m0 + srow) * (long)K + scol;
  const short* Bg = Bt + (n0 + srow) * (long)K + scol;
  const long rs64 = (long)64 * K;

  // ds-read bases: frag row&7 == l16&7; byte = row*128 + (chunk^(l16&7))*16
  const int x7  = l16 & 7;
  const int xo0 = ((0 + quad) ^ x7) * 16;   // K 0-31
  const int xo1 = ((4 + quad) ^ x7) * 16;   // K 32-63
  const int aRow = (wm + l16) * 128;
  const int bRow = (wn + l16) * 128;

  // half-stage: h=0 -> A rows 0-127 + B rows 0-63; h=1 -> the rest (3 gl16)
  auto STAGE_HALF = [&](int t2, int h) {
    const int bb = t2 % 3;
    const long k0 = (long)t2 << 6;
    gl16(Ag + k0 + (h * 2 + 0) * rs64, (char*)As[bb] + (h * 2 + 0) * 8192 + tid * 16);
    gl16(Ag + k0 + (h * 2 + 1) * rs64, (char*)As[bb] + (h * 2 + 1) * 8192 + tid * 16);
    gl16(Bg + k0 + h * rs64,           (char*)Bs[bb] + h * 8192 + tid * 16);
  };

  const int nt = K >> 6;     // 16 for K=1024
  STAGE_HALF(0, 0); STAGE_HALF(0, 1);
  STAGE_HALF(1, 0); STAGE_HALF(1, 1);

  for (int t = 0; t < nt; ++t) {
    // retire tile t's 6 loads; keep tile t+1's 6 in flight (never drain)
    if (t + 1 < nt) { asm volatile("s_waitcnt vmcnt(6)" ::: "memory"); }
    else            { asm volatile("s_waitcnt vmcnt(0)" ::: "memory"); }
    __builtin_amdgcn_sched_barrier(0);
    __builtin_amdgcn_s_barrier();        // buf[t%3] ready for ALL waves
    __builtin_amdgcn_sched_barrier(0);

    const char* Ab = (const char*)As[t % 3];
    const char* Bb = (const char*)Bs[t % 3];

#pragma unroll
    for (int ph = 0; ph < 2; ++ph) {
      const int xo = ph ? xo1 : xo0;
      short8 af[4], bfv[4];
#pragma unroll
      for (int i = 0; i < 4; ++i)
        af[i] = *(const short8*)(Ab + aRow + i * 2048 + xo);
#pragma unroll
      for (int j = 0; j < 4; ++j)
        bfv[j] = *(const short8*)(Bb + bRow + j * 2048 + xo);
      if (t + 2 < nt) STAGE_HALF(t + 2, ph);   // ring slot free (readers t-1)
      __builtin_amdgcn_s_setprio(1);
#pragma unroll
      for (int i = 0; i < 4; ++i)
#pragma unroll
        for (int j = 0; j < 4; ++j)
          acc[i][j] = __builtin_amdgcn_mfma_f32_16x16x32_bf16(af[i], bfv[j], acc[i][j], 0, 0, 0);
      __builtin_amdgcn_s_setprio(0);
      if (ph == 0) {                       // phase-lock the MFMA clusters
        __builtin_amdgcn_s_barrier();
        __builtin_amdgcn_sched_barrier(0);
      }
    }
  }

#pragma unroll
  for (int j = 0; j < 4; ++j) {
    const long col = n0 + wn + j * 16 + l16;
    float bv = 0.f;
    if (MODE == 1)
      bv = isf32 ? ((const float*)bias)[col] : bf2f(((const short*)bias)[col]);
#pragma unroll
    for (int i = 0; i < 4; ++i) {
      const long row0 = m0 + wm + i * 16 + quad * 4;
      if (MODE == 2 && col >= 2048) {
        // V^T: 4 consecutive t per thread -> one 8B store
        const long bb = row0 >> 11, t0 = row0 & 2047;
        const long hd = col - 2048;            // h*64 + d
        shrt4 v4;
#pragma unroll
        for (int r = 0; r < 4; ++r) v4[r] = f2bf(acc[i][j][r]);
        *(shrt4*)&vt[((bb * 16 + (hd >> 6)) * 64 + (hd & 63)) * 2048 + t0] = v4;
      } else {
#pragma unroll
        for (int r = 0; r < 4; ++r) {
          const long row = row0 + r;
          const float val = acc[i][j][r] + bv;
          if (MODE == 2) {
            const float vq = (col < 1024) ? val * QSCALE : val;
            ((short*)C)[row * 2048 + col] = f2bf(vq);
          } else {
            if (isf32) ((float*)C)[row * (long)N + col] = val;
            else       ((short*)C)[row * (long)N + col] = f2bf(val);
          }
        }
      }
    }
  }
}

// ---------------------------------------------------------------------------
// 64x64 transpose + cast-to-bf16: dst[C,R] = (bf16)src[R,C]^T
// ---------------------------------------------------------------------------
__global__ __launch_bounds__(256) void transpose64(
    const void* __restrict__ src, short* __restrict__ dst, int R, int C)
{
  __shared__ __align__(16) short tile[64][72];
  const int isf32 = g_isf32;
  const int tid = threadIdx.x;
  const long r0 = (long)blockIdx.y * 64;
  const long c0 = (long)blockIdx.x * 64;
#pragma unroll
  for (int it = 0; it < 2; ++it) {
    int idx = it * 256 + tid;
    int rr = idx >> 3, ch = idx & 7;
    const long off = (r0 + rr) * C + c0 + ch * 8;
    short8 v;
    if (isf32) {
      const float* s = (const float*)src + off;
      v = pack8(*(const f32x4*)s, *(const f32x4*)(s + 4));
    } else {
      v = *(const short8*)((const short*)src + off);
    }
    *(short8*)&tile[rr][ch * 8] = v;
  }
  __syncthreads();
#pragma unroll
  for (int it = 0; it < 2; ++it) {
    int idx = it * 256 + tid;
    int cc = idx >> 3, ch = idx & 7;
    short8 v;
#pragma unroll
    for (int jj = 0; jj < 8; ++jj) v[jj] = tile[ch * 8 + jj][cc];
    *(short8*)&dst[(c0 + cc) * R + r0 + ch * 8] = v;
  }
}

// ---------------------------------------------------------------------------
// Flash attention (causal) — unchanged from round 8/9.
// ---------------------------------------------------------------------------
__global__ __launch_bounds__(256) void attn_fwd(
    const short* __restrict__ qk, const short* __restrict__ vt,
    short* __restrict__ out)
{
  __shared__ __align__(16) short Ks[2][64][32];   // [d-half][k-row][d%32]
  __shared__ __align__(16) short Vs[2][64][32];   // [k-half][d][k%32]
  __shared__ __align__(16) short Pw[4][16][76];   // wave-private P, bf16
  const int tid = threadIdx.x;
  const int lane = tid & 63, wave = tid >> 6;
  const int quad = lane >> 4, l16 = lane & 15;
  const int bh = blockIdx.x;
  const int b = bh >> 4, h = bh & 15;
  const int jq = (int)gridDim.y - 1 - (int)blockIdx.y;  // big-work blocks first
  const int qbase = jq * 64 + wave * 16;

  // Q A-frags (rows qbase+l16, two 32-wide d slices); Q is pre-scaled
  const short* qp = qk + ((long)(b * 2048 + qbase + l16)) * 2048 + h * 64 + quad * 8;
  const short8 aq0 = *(const short8*)qp;
  const short8 aq1 = *(const short8*)(qp + 32);

  // staging sources: row sr (k-row for K, d for V), 16B chunk sc_
  const int sr = tid >> 2, sc_ = tid & 3;
  const short* kg = qk + (long)b * 2048 * 2048 + 1024 + h * 64 + (long)sr * 2048 + sc_ * 8;
  const short* vg = vt + ((long)bh * 64 + sr) * 2048 + sc_ * 8;

  f32x4 o[4] = {};
  float m_run[4], l_run[4];
#pragma unroll
  for (int r = 0; r < 4; ++r) { m_run[r] = -1e30f; l_run[r] = 0.f; }

  // ------------------- main tiles: k0+63 < qbase, no masking ----------------
  for (int kt = 0; kt < jq; ++kt) {
    const int k0 = kt * 64;

    __syncthreads();                            // prev-tile readers done
    gl16(kg + (long)k0 * 2048,      (char*)Ks + tid * 16);         // d 0-31
    gl16(kg + (long)k0 * 2048 + 32, (char*)Ks + 4096 + tid * 16);  // d 32-63
    gl16(vg + k0,                   (char*)Vs + tid * 16);         // k 0-31
    gl16(vg + k0 + 32,              (char*)Vs + 4096 + tid * 16);  // k 32-63
    __syncthreads();                            // staging visible

    // S = Q K^T : 4 col-tiles, kdim 64 = 2 MFMA each (already log2-scaled)
    f32x4 s[4];
#pragma unroll
    for (int c = 0; c < 4; ++c) {
      short8 kf0 = *(const short8*)&Ks[0][c * 16 + l16][quad * 8];
      short8 kf1 = *(const short8*)&Ks[1][c * 16 + l16][quad * 8];
      f32x4 z = {};
      z = __builtin_amdgcn_mfma_f32_16x16x32_bf16(aq0, kf0, z, 0, 0, 0);
      z = __builtin_amdgcn_mfma_f32_16x16x32_bf16(aq1, kf1, z, 0, 0, 0);
      s[c] = z;
    }

    // row max: tile-combine then DPP butterfly (pure VALU)
    float mx[4];
#pragma unroll
    for (int r = 0; r < 4; ++r)
      mx[r] = dpp_max16(fmaxf(fmaxf(s[0][r], s[1][r]), fmaxf(s[2][r], s[3][r])));

    // T13 defer-max: rescale only when some row grew by > 8 (log2 domain)
    int grow = 0;
#pragma unroll
    for (int r = 0; r < 4; ++r) grow |= (mx[r] > m_run[r] + 8.f);
    if (__any(grow)) {
#pragma unroll
      for (int r = 0; r < 4; ++r) {
        const float mn = fmaxf(m_run[r], mx[r]);
        const float al = __builtin_amdgcn_exp2f(m_run[r] - mn);
        m_run[r] = mn;
        l_run[r] *= al;
#pragma unroll
        for (int i = 0; i < 4; ++i) o[i][r] *= al;
      }
    }

    // P = exp2(S - m), accumulate l, store bf16 to wave-private LDS
#pragma unroll
    for (int c = 0; c < 4; ++c)
#pragma unroll
      for (int r = 0; r < 4; ++r) {
        const float p = __builtin_amdgcn_exp2f(s[c][r] - m_run[r]);
        l_run[r] += p;
        Pw[wave][quad * 4 + r][c * 16 + l16] = pbf(p);
      }

    // O += P V
    {
      short8 pf0 = *(const short8*)&Pw[wave][l16][quad * 8];
      short8 pf1 = *(const short8*)&Pw[wave][l16][32 + quad * 8];
#pragma unroll
      for (int i = 0; i < 4; ++i) {
        short8 vf0 = *(const short8*)&Vs[0][i * 16 + l16][quad * 8];
        o[i] = __builtin_amdgcn_mfma_f32_16x16x32_bf16(pf0, vf0, o[i], 0, 0, 0);
        short8 vf1 = *(const short8*)&Vs[1][i * 16 + l16][quad * 8];
        o[i] = __builtin_amdgcn_mfma_f32_16x16x32_bf16(pf1, vf1, o[i], 0, 0, 0);
      }
    }
  }

  // ------------------- diagonal tile: kt = jq ------------------------------
  {
    const int k0 = jq * 64;

    __syncthreads();
    gl16(kg + (long)k0 * 2048,      (char*)Ks + tid * 16);
    gl16(kg + (long)k0 * 2048 + 32, (char*)Ks + 4096 + tid * 16);
    gl16(vg + k0,                   (char*)Vs + tid * 16);
    gl16(vg + k0 + 32,              (char*)Vs + 4096 + tid * 16);
    __syncthreads();

    // live c-tiles: c <= wave.  Only c == wave straddles the diagonal.
    f32x4 s[4];
    float mx[4];
#pragma unroll
    for (int r = 0; r < 4; ++r) mx[r] = -1e30f;
#pragma unroll
    for (int c = 0; c < 4; ++c) {
      if (c > wave) continue;                   // wave-uniform
      short8 kf0 = *(const short8*)&Ks[0][c * 16 + l16][quad * 8];
      short8 kf1 = *(const short8*)&Ks[1][c * 16 + l16][quad * 8];
      f32x4 z = {};
      z = __builtin_amdgcn_mfma_f32_16x16x32_bf16(aq0, kf0, z, 0, 0, 0);
      z = __builtin_amdgcn_mfma_f32_16x16x32_bf16(aq1, kf1, z, 0, 0, 0);
      if (c == wave) {
#pragma unroll
        for (int r = 0; r < 4; ++r)
          z[r] = (l16 > quad * 4 + r) ? -1e30f : z[r];
      }
      s[c] = z;
#pragma unroll
      for (int r = 0; r < 4; ++r) mx[r] = fmaxf(mx[r], z[r]);
    }
#pragma unroll
    for (int r = 0; r < 4; ++r) mx[r] = dpp_max16(mx[r]);

    int grow = 0;
#pragma unroll
    for (int r = 0; r < 4; ++r) grow |= (mx[r] > m_run[r] + 8.f);
    if (__any(grow)) {
#pragma unroll
      for (int r = 0; r < 4; ++r) {
        const float mn = fmaxf(m_run[r], mx[r]);
        const float al = __builtin_amdgcn_exp2f(m_run[r] - mn);
        m_run[r] = mn;
        l_run[r] *= al;
#pragma unroll
        for (int i = 0; i < 4; ++i) o[i][r] *= al;
      }
    }

#pragma unroll
    for (int c = 0; c < 4; ++c) {
      if (c <= wave) {
#pragma unroll
        for (int r = 0; r < 4; ++r) {
          const float p = __builtin_amdgcn_exp2f(s[c][r] - m_run[r]);
          l_run[r] += p;
          Pw[wave][quad * 4 + r][c * 16 + l16] = pbf(p);
        }
      } else if (c < 2 || wave >= 2) {
        // dead c inside a live V-half: zero-fill so PV reads zeros
#pragma unroll
        for (int r = 0; r < 4; ++r)
          Pw[wave][quad * 4 + r][c * 16 + l16] = 0;
      }
    }

    {
      short8 pf0 = *(const short8*)&Pw[wave][l16][quad * 8];
#pragma unroll
      for (int i = 0; i < 4; ++i) {
        short8 vf0 = *(const short8*)&Vs[0][i * 16 + l16][quad * 8];
        o[i] = __builtin_amdgcn_mfma_f32_16x16x32_bf16(pf0, vf0, o[i], 0, 0, 0);
      }
      if (wave >= 2) {
        short8 pf1 = *(const short8*)&Pw[wave][l16][32 + quad * 8];
#pragma unroll
        for (int i = 0; i < 4; ++i) {
          short8 vf1 = *(const short8*)&Vs[1][i * 16 + l16][quad * 8];
          o[i] = __builtin_amdgcn_mfma_f32_16x16x32_bf16(pf1, vf1, o[i], 0, 0, 0);
        }
      }
    }
  }

  // final row-sum of per-lane l (DPP butterfly), then normalize + store
#pragma unroll
  for (int r = 0; r < 4; ++r) l_run[r] = dpp_sum16(l_run[r]);
  float inv[4];
#pragma unroll
  for (int r = 0; r < 4; ++r) inv[r] = 1.0f / l_run[r];
  short* op = out + ((long)(b * 2048 + qbase + quad * 4)) * 1024 + h * 64;
#pragma unroll
  for (int i = 0; i < 4; ++i)
#pragma unroll
    for (int r = 0; r < 4; ++r)
      op[(long)r * 1024 + i * 16 + l16] = f2bf(o[i][r] * inv[r]);
}

// ---------------------------------------------------------------------------
// plan-B epilogue copy: projout (qk region) -> d_out
// ---------------------------------------------------------------------------
__global__ __launch_bounds__(256) void copy_out(const void* __restrict__ src,
                                                void* __restrict__ dst)
{
  const long n16 = g_isf32 ? 2097152L : 1048576L;   // uint4 chunks
  const uint4* s = (const uint4*)src;
  uint4* d = (uint4*)dst;
  for (long i = (long)blockIdx.x * 256 + threadIdx.x; i < n16;
       i += (long)gridDim.x * 256)
    d[i] = s[i];
}

// ---------------------------------------------------------------------------
extern "C" void kernel_launch(void* const* d_in, const int* in_sizes, int n_in,
                              void* d_out, int out_size, void* d_ws, size_t ws_size,
                              hipStream_t stream)
{
  const void* x      = d_in[0];   // [8192,1024]  fp32 or bf16
  const void* w_qkv  = d_in[1];   // [1024,3072]
  const void* w_proj = d_in[2];   // [1024,1024]
  const void* b_proj = d_in[3];   // [1024]

  short* ws = (short*)d_ws;
  const bool planA = ws_size >= 67108864ULL;   // 64 MiB

  short* qk  = ws;                 // [8192,2048] bf16    = 32 MiB
  short* vtp = ws + 16777216L;     // [64][64][2048] bf16 = 16 MiB

  short *wqkvT, *attnb, *wprojT, *xbf;
  void*  projC;
  if (planA) {
    attnb  = ws + 25165824L;       // 16 MiB, [48,64) MiB of ws
    wqkvT  = attnb;                // aliased; dead once qkv GEMM reads done
    wprojT = qk;                   // aliased; written after attn_fwd
    xbf    = (short*)d_out;        // 16 MiB in dead d_out; dead after qkv GEMM
    projC  = d_out;
  } else {
    wqkvT  = (short*)d_out;        // d_out dead until the end
    xbf    = (short*)d_out + 3145728L;
    attnb  = (short*)d_out;        // overwrites wqkvT/xbf after both dead
    wprojT = vtp;                  // vtp dead after attn_fwd
    projC  = qk;                   // qk dead after attn_fwd (32 MiB fits fp32)
  }

  // 0. detect dtype; convert x to bf16
  detect_dtype<<<64, 256, 0, stream>>>((const unsigned short*)w_qkv);
  cvt_x<<<4096, 256, 0, stream>>>(x, xbf);
  // 1. W_qkv^T (cast to bf16)
  transpose64<<<dim3(3072 / 64, 1024 / 64), 256, 0, stream>>>(w_qkv, wqkvT, 1024, 3072);
  // 2. qkv GEMM, split epilogue (Q pre-scaled; Q,K row-major bf16; V -> vtp)
  gemm_bt<2><<<dim3(3072 / 128, 8192 / 256), 512, 0, stream>>>(
      xbf, wqkvT, nullptr, qk, vtp, 8192, 3072, 1024);
  // 3. flash attention (LDS-staged K/V)
  attn_fwd<<<dim3(64, 32), 256, 0, stream>>>(qk, vtp, attnb);
  // 4. W_proj^T (cast to bf16)
  transpose64<<<dim3(1024 / 64, 1024 / 64), 256, 0, stream>>>(w_proj, wprojT, 1024, 1024);
  // 5. output projection + bias
  gemm_bt<1><<<dim3(1024 / 128, 8192 / 256), 512, 0, stream>>>(
      attnb, wprojT, b_proj, projC, nullptr, 8192, 1024, 1024);
  // 6. plan-B: move result into d_out
  if (!planA)
    copy_out<<<2048, 256, 0, stream>>>(projC, d_out);
}